// Round 3
// baseline (704.844 us; speedup 1.0000x reference)
//
#include <hip/hip_runtime.h>

// Fused dequant-gather embedding:
//   out[t, d] = (float)qweight[x[t], d] * scales[x[t], d/128]
// T = 32*2048 = 65536 tokens, D = 1024, G = 8 (group size 128).
// Memory-bound: ~540 MB of mandatory traffic -> ~90-150 us floor.
//
// R3 = R2 with the compile fix: __builtin_nontemporal_store needs a NATIVE
// clang vector type (ext_vector_type), not HIP's float4 class.
//  - #pragma unroll 4: 4 independent {scale, int4} load pairs in flight per
//    thread to hide random-gather latency (~900 cyc HBM miss, ~200 cyc L2 hit).
//  - nontemporal stores: output is write-once; keep the 268 MB write stream
//    from evicting gathered qweight rows in L2/L3.

#define NGROUPS  8

typedef float f32x4 __attribute__((ext_vector_type(4)));
typedef int   i32x4 __attribute__((ext_vector_type(4)));

__global__ __launch_bounds__(256) void quant_embed_gather_kernel(
    const int*   __restrict__ x,       // [T] token row indices (int32)
    const int*   __restrict__ qw,      // [VOCAB, DIM] int4 codes as int32
    const float* __restrict__ sc,      // [VOCAB, NGROUPS]
    float*       __restrict__ out,     // [T, DIM]
    int total_chunks)                  // T * 256 float4-chunks
{
    const int tid    = blockIdx.x * blockDim.x + threadIdx.x;
    const int stride = gridDim.x * blockDim.x;   // 524288 -> 32 trips/thread

    #pragma unroll 4
    for (int c = tid; c < total_chunks; c += stride) {
        const int token  = c >> 8;      // chunk / 256
        const int within = c & 255;     // chunk within the row (wave-uniform row)
        const int row    = x[token];

        const int g   = within >> 5;    // (within*4) / 128
        const float s = sc[row * NGROUPS + g];

        const i32x4 q = *reinterpret_cast<const i32x4*>(
            qw + (((long long)row << 10) + (within << 2)));

        f32x4 o;
        o.x = (float)q.x * s;
        o.y = (float)q.y * s;
        o.z = (float)q.z * s;
        o.w = (float)q.w * s;

        __builtin_nontemporal_store(o, reinterpret_cast<f32x4*>(out + ((long long)c << 2)));
    }
}

extern "C" void kernel_launch(void* const* d_in, const int* in_sizes, int n_in,
                              void* d_out, int out_size, void* d_ws, size_t ws_size,
                              hipStream_t stream) {
    const int*   x  = (const int*)d_in[0];     // [65536]
    const int*   qw = (const int*)d_in[1];     // [128000*1024]
    const float* sc = (const float*)d_in[2];   // [128000*8]
    float* out = (float*)d_out;                // [65536*1024]

    const int total_chunks = out_size / 4;     // 16,777,216
    const int block = 256;
    const int grid  = 2048;                    // 8192 waves: full 256-CU occupancy

    quant_embed_gather_kernel<<<grid, block, 0, stream>>>(x, qw, sc, out, total_chunks);
}